// Round 5
// baseline (278.588 us; speedup 1.0000x reference)
//
#include <hip/hip_runtime.h>

// GCN 2-layer. R12 = R9 pipeline restructured around precomputed global degrees.
// R10/R11 (cooperative fusion) killed the container twice -> abandoned: grid.sync
// co-residency risk / coop-launch capture hazard not worth it. Same structural win
// done safely: per-node in-degree is global -> compute it IN k_sort via distributed
// global atomics (3.2M adds over 100K addresses; the pipelined case, unlike R6's
// 2-address tail). Then u[] is complete before any bucket kernel:
//  k_sort     : bucket sort by dst>>7 + global deg histogram
//  k_u        : u[i] = rsqrt(deg[i]+1) * x[i]            (tiny N-kernel)
//  k_csr_agg1 : per bucket: seg = scan(deg) (NO count pass), place srcs into LDS,
//               writeback sorted srcs (for k_agg2), fused segmented sum of u[src]
//               + 64-wide MLP -> w. agg1's whole packed re-read + rptr eliminated.
//  k_agg2     : seg = scan(deg), read sorted srcs, float2 gather-sum + log_softmax
//               -> per-block partial (plain store)
//  k_reduce_final : sum partials + 1/N
// packed word (pre-sort): bits[16:0]=src, bits[23:17]=dst&127; post-sort: plain src.
// R9 lessons kept: atomic-free segmented aggregation, 4 threads/node register loop.

#define TPB 512
#define SORT_BLK 256
#define BSHIFT 7
#define BNODES 128
#define MAXBUCK 1024
#define BSTRIDE 6144      // words per bucket region; mean 4092, sigma ~64 -> 32 sigma

// ---------------- bucket sort + global degree histogram ----------------

__global__ __launch_bounds__(TPB) void k_sort(const int* __restrict__ ei, int E, int epb,
                                              int nbuck, int* __restrict__ gcur,
                                              unsigned* __restrict__ packed,
                                              int* __restrict__ deg) {
    __shared__ int h[MAXBUCK];
    for (int b = threadIdx.x; b < nbuck; b += TPB) h[b] = 0;
    __syncthreads();
    const int4* d4 = (const int4*)(ei + E);
    int nq = epb >> 2;
    int q0 = blockIdx.x * nq;
    for (int j = threadIdx.x; j < nq; j += TPB) {
        int q = q0 + j;
        int e = q << 2;
        if (e + 3 < E) {
            int4 v = d4[q];
            atomicAdd(&h[v.x >> BSHIFT], 1);
            atomicAdd(&h[v.y >> BSHIFT], 1);
            atomicAdd(&h[v.z >> BSHIFT], 1);
            atomicAdd(&h[v.w >> BSHIFT], 1);
            atomicAdd(&deg[v.x], 1);
            atomicAdd(&deg[v.y], 1);
            atomicAdd(&deg[v.z], 1);
            atomicAdd(&deg[v.w], 1);
        } else {
            for (int k = 0; k < 4; ++k)
                if (e + k < E) {
                    int d = (ei + E)[e + k];
                    atomicAdd(&h[d >> BSHIFT], 1);
                    atomicAdd(&deg[d], 1);
                }
        }
    }
    __syncthreads();
    for (int b = threadIdx.x; b < nbuck; b += TPB) {
        int c = h[b];
        h[b] = c ? atomicAdd(&gcur[b], c) : 0;
    }
    __syncthreads();
    const int4* s4 = (const int4*)ei;
    for (int j = threadIdx.x; j < nq; j += TPB) {
        int q = q0 + j;
        int e = q << 2;
        if (e + 3 < E) {
            int4 vs = s4[q];
            int4 vd = d4[q];
            int b, p;
            b = vd.x >> BSHIFT; p = atomicAdd(&h[b], 1);
            packed[b * BSTRIDE + p] = ((unsigned)(vd.x & (BNODES - 1)) << 17) | (unsigned)vs.x;
            b = vd.y >> BSHIFT; p = atomicAdd(&h[b], 1);
            packed[b * BSTRIDE + p] = ((unsigned)(vd.y & (BNODES - 1)) << 17) | (unsigned)vs.y;
            b = vd.z >> BSHIFT; p = atomicAdd(&h[b], 1);
            packed[b * BSTRIDE + p] = ((unsigned)(vd.z & (BNODES - 1)) << 17) | (unsigned)vs.z;
            b = vd.w >> BSHIFT; p = atomicAdd(&h[b], 1);
            packed[b * BSTRIDE + p] = ((unsigned)(vd.w & (BNODES - 1)) << 17) | (unsigned)vs.w;
        } else {
            for (int k = 0; k < 4; ++k) {
                int ee = e + k;
                if (ee < E) {
                    int s = ei[ee], d = ei[E + ee];
                    int b = d >> BSHIFT;
                    int p = atomicAdd(&h[b], 1);
                    packed[b * BSTRIDE + p] = ((unsigned)(d & (BNODES - 1)) << 17) | (unsigned)s;
                }
            }
        }
    }
}

// ---------------- u = rsqrt(deg+1) * x ----------------

__global__ __launch_bounds__(TPB) void k_u(const int* __restrict__ deg,
                                           const float* __restrict__ x,
                                           float* __restrict__ u, int N) {
    int i = blockIdx.x * TPB + threadIdx.x;
    if (i < N) u[i] = rsqrtf((float)(deg[i] + 1)) * x[i];
}

// ------- per-bucket: scan(deg) -> place -> writeback + fused agg1 + MLP -------

__global__ __launch_bounds__(TPB) void k_csr_agg1(unsigned* __restrict__ packed,
                                                  const int* __restrict__ deg,
                                                  const float* __restrict__ u,
                                                  const float* __restrict__ W1,
                                                  const float* __restrict__ b1,
                                                  const float* __restrict__ W2,
                                                  float2* __restrict__ w, int N) {
    __shared__ unsigned stage[BSTRIDE];
    __shared__ int seg[BNODES + 1];
    __shared__ int cur[BNODES];
    __shared__ float sW1[64], sb1[64], sW2[128];
    const int tid = threadIdx.x;
    const int b = blockIdx.x;
    if (tid < 64) { sW1[tid] = W1[tid]; sb1[tid] = b1[tid]; }
    else if (tid < 192) sW2[tid - 64] = W2[tid - 64];
    // ---- seg offsets from global deg (no count pass) ----
    int mydeg = 0;
    if (tid < BNODES) {
        int node = (b << BSHIFT) + tid;
        mydeg = (node < N) ? deg[node] : 0;
        seg[tid] = mydeg;
    }
    __syncthreads();
    for (int d = 1; d < BNODES; d <<= 1) {
        int add = 0;
        if (tid < BNODES && tid >= d) add = seg[tid - d];
        __syncthreads();
        if (tid < BNODES) seg[tid] += add;
        __syncthreads();
    }
    if (tid == BNODES - 1) seg[BNODES] = seg[tid];        // total (inclusive)
    if (tid < BNODES) { seg[tid] -= mydeg; cur[tid] = seg[tid]; }
    __syncthreads();
    const int sz = seg[BNODES];
    // ---- placement pass (shared cursors; ~8 LDS atomics/thread) ----
    unsigned* base = packed + (size_t)b * BSTRIDE;
    const uint4* base4 = (const uint4*)base;
    int nq4 = sz >> 2;
    int half = nq4 >> 1;
    for (int j = tid; j < half; j += TPB) {
        uint4 p = base4[j];
        uint4 q = base4[j + half];
        int pos;
        pos = atomicAdd(&cur[(p.x >> 17) & 127], 1); stage[pos] = p.x & 0x1FFFF;
        pos = atomicAdd(&cur[(p.y >> 17) & 127], 1); stage[pos] = p.y & 0x1FFFF;
        pos = atomicAdd(&cur[(p.z >> 17) & 127], 1); stage[pos] = p.z & 0x1FFFF;
        pos = atomicAdd(&cur[(p.w >> 17) & 127], 1); stage[pos] = p.w & 0x1FFFF;
        pos = atomicAdd(&cur[(q.x >> 17) & 127], 1); stage[pos] = q.x & 0x1FFFF;
        pos = atomicAdd(&cur[(q.y >> 17) & 127], 1); stage[pos] = q.y & 0x1FFFF;
        pos = atomicAdd(&cur[(q.z >> 17) & 127], 1); stage[pos] = q.z & 0x1FFFF;
        pos = atomicAdd(&cur[(q.w >> 17) & 127], 1); stage[pos] = q.w & 0x1FFFF;
    }
    for (int j = half * 8 + tid; j < sz; j += TPB) {       // tail < 12 words
        unsigned p = base[j];
        int pos = atomicAdd(&cur[(p >> 17) & 127], 1);
        stage[pos] = p & 0x1FFFF;
    }
    __syncthreads();
    // ---- coalesced writeback of sorted srcs (consumed by k_agg2) ----
    for (int k = tid; k < sz; k += TPB) base[k] = stage[k];
    // ---- fused segmented sum of u[src] + MLP (4 threads/node) ----
    int t = tid >> 2, k4 = tid & 3;
    int s0 = seg[t], s1 = seg[t + 1];
    float s = 0.f;
    for (int j = s0 + k4; j < s1; j += 4) s += u[stage[j]];
    s += __shfl_xor(s, 1, 64);
    s += __shfl_xor(s, 2, 64);
    int node = (b << BSHIFT) + t;
    if (k4 == 0 && node < N) {
        float di = rsqrtf((float)((s1 - s0) + 1));
        float sv = di * (s + u[node]);           // self-loop term dinv*u
        float z0 = 0.f, z1 = 0.f;
        #pragma unroll
        for (int j = 0; j < 64; ++j) {
            float h = fmaxf(fmaf(sv, sW1[j], sb1[j]), 0.f);
            z0 = fmaf(h, sW2[2 * j], z0);
            z1 = fmaf(h, sW2[2 * j + 1], z1);
        }
        w[node] = make_float2(di * z0, di * z1); // pre-scaled by dinv[src]
    }
}

// ---- layer-2: scan(deg) -> segmented float2 sum + log_softmax + partial ----

__global__ __launch_bounds__(TPB) void k_agg2(const unsigned* __restrict__ sorted,
                                              const int* __restrict__ deg,
                                              const float2* __restrict__ w,
                                              const float* __restrict__ b2,
                                              float* __restrict__ accum, int N) {
    __shared__ int seg[BNODES + 1];
    const int tid = threadIdx.x;
    const int b = blockIdx.x;
    int mydeg = 0;
    if (tid < BNODES) {
        int node = (b << BSHIFT) + tid;
        mydeg = (node < N) ? deg[node] : 0;
        seg[tid] = mydeg;
    }
    __syncthreads();
    for (int d = 1; d < BNODES; d <<= 1) {
        int add = 0;
        if (tid < BNODES && tid >= d) add = seg[tid - d];
        __syncthreads();
        if (tid < BNODES) seg[tid] += add;
        __syncthreads();
    }
    if (tid == BNODES - 1) seg[BNODES] = seg[tid];
    if (tid < BNODES) seg[tid] -= mydeg;
    __syncthreads();
    int t = tid >> 2, k4 = tid & 3;
    const unsigned* base = sorted + (size_t)b * BSTRIDE;
    int s0 = seg[t], s1 = seg[t + 1];
    float sx = 0.f, sy = 0.f;
    for (int j = s0 + k4; j < s1; j += 4) {
        float2 v = w[base[j]];
        sx += v.x;
        sy += v.y;
    }
    sx += __shfl_xor(sx, 1, 64); sx += __shfl_xor(sx, 2, 64);
    sy += __shfl_xor(sy, 1, 64); sy += __shfl_xor(sy, 2, 64);
    int node = (b << BSHIFT) + t;
    float l0 = 0.f, l1 = 0.f;
    if (k4 == 0 && node < N) {
        float di = rsqrtf((float)((s1 - s0) + 1));
        float2 wi = w[node];
        float a0 = di * (sx + wi.x) + b2[0];
        float a1 = di * (sy + wi.y) + b2[1];
        float m = fmaxf(a0, a1);
        float lse = m + logf(expf(a0 - m) + expf(a1 - m));
        l0 = a0 - lse;
        l1 = a1 - lse;
    }
    #pragma unroll
    for (int off = 32; off > 0; off >>= 1) {
        l0 += __shfl_down(l0, off, 64);
        l1 += __shfl_down(l1, off, 64);
    }
    __shared__ float r0[TPB / 64], r1[TPB / 64];
    int wid = tid >> 6, lane = tid & 63;
    if (lane == 0) { r0[wid] = l0; r1[wid] = l1; }
    __syncthreads();
    if (tid == 0) {
        float t0 = 0.f, t1 = 0.f;
        #pragma unroll
        for (int kk = 0; kk < TPB / 64; ++kk) { t0 += r0[kk]; t1 += r1[kk]; }
        accum[2 * b]     = t0;   // private slot, plain store
        accum[2 * b + 1] = t1;
    }
}

// ---------------- final reduction over per-block partials ----------------

#define RTPB 1024
__global__ __launch_bounds__(RTPB) void k_reduce_final(const float* __restrict__ accum,
                                                       int nb, float* __restrict__ out,
                                                       float invN) {
    float t0 = 0.f, t1 = 0.f;
    for (int i = threadIdx.x; i < nb; i += RTPB) {
        t0 += accum[2 * i];
        t1 += accum[2 * i + 1];
    }
    #pragma unroll
    for (int off = 32; off > 0; off >>= 1) {
        t0 += __shfl_down(t0, off, 64);
        t1 += __shfl_down(t1, off, 64);
    }
    __shared__ float s0[RTPB / 64], s1[RTPB / 64];
    int wid = threadIdx.x >> 6, lane = threadIdx.x & 63;
    if (lane == 0) { s0[wid] = t0; s1[wid] = t1; }
    __syncthreads();
    if (threadIdx.x == 0) {
        float a = 0.f, b = 0.f;
        #pragma unroll
        for (int k = 0; k < RTPB / 64; ++k) { a += s0[k]; b += s1[k]; }
        out[0] = a * invN;
        out[1] = b * invN;
    }
}

__global__ void k_finalize(const float* __restrict__ accum, float* __restrict__ out, float invN) {
    out[0] = accum[0] * invN;
    out[1] = accum[1] * invN;
}

// ---------------- fallback (global-atomic path) ----------------

#define FTPB 256
__global__ void k_hist(const int* __restrict__ dst, int E, int* __restrict__ deg) {
    int e = blockIdx.x * FTPB + threadIdx.x;
    if (e < E) atomicAdd(&deg[dst[e]], 1);
}
__global__ void k_dinv_u(const int* __restrict__ deg, const float* __restrict__ x,
                         float* __restrict__ dinv, float* __restrict__ u, int N) {
    int i = blockIdx.x * FTPB + threadIdx.x;
    if (i < N) {
        float di = rsqrtf((float)(deg[i] + 1));
        dinv[i] = di;
        u[i] = di * x[i];
    }
}
__global__ void k_scatter1(const int* __restrict__ ei, int E,
                           const float* __restrict__ u, float* __restrict__ t) {
    int e = blockIdx.x * FTPB + threadIdx.x;
    if (e < E) atomicAdd(&t[ei[E + e]], u[ei[e]]);
}
__global__ void k_node_mid_fb(const float* __restrict__ dinv, const float* __restrict__ u,
                              const float* __restrict__ t,
                              const float* __restrict__ W1, const float* __restrict__ b1,
                              const float* __restrict__ W2, float2* __restrict__ w, int N) {
    __shared__ float sW1[64], sb1[64], sW2[128];
    if (threadIdx.x < 64) { sW1[threadIdx.x] = W1[threadIdx.x]; sb1[threadIdx.x] = b1[threadIdx.x]; }
    if (threadIdx.x < 128) sW2[threadIdx.x] = W2[threadIdx.x];
    __syncthreads();
    int i = blockIdx.x * FTPB + threadIdx.x;
    if (i < N) {
        float di = dinv[i];
        float s = di * (t[i] + u[i]);
        float z0 = 0.f, z1 = 0.f;
        #pragma unroll
        for (int j = 0; j < 64; ++j) {
            float h = fmaxf(fmaf(s, sW1[j], sb1[j]), 0.f);
            z0 = fmaf(h, sW2[2 * j], z0);
            z1 = fmaf(h, sW2[2 * j + 1], z1);
        }
        w[i] = make_float2(di * z0, di * z1);
    }
}
__global__ void k_scatter2(const int* __restrict__ ei, int E,
                           const float2* __restrict__ w, float* __restrict__ acc) {
    int e = blockIdx.x * FTPB + threadIdx.x;
    if (e < E) {
        float2 ws = w[ei[e]];
        int d = ei[E + e];
        atomicAdd(&acc[2 * d], ws.x);
        atomicAdd(&acc[2 * d + 1], ws.y);
    }
}
__global__ void k_node_out_fb(const float* __restrict__ dinv, const float2* __restrict__ w,
                              const float2* __restrict__ acc, const float* __restrict__ b2,
                              float* __restrict__ accum, int N) {
    int i = blockIdx.x * FTPB + threadIdx.x;
    float l0 = 0.f, l1 = 0.f;
    if (i < N) {
        float di = dinv[i];
        float2 a = acc[i];
        float2 ww = w[i];
        float a0 = di * (a.x + ww.x) + b2[0];
        float a1 = di * (a.y + ww.y) + b2[1];
        float m = fmaxf(a0, a1);
        float lse = m + logf(expf(a0 - m) + expf(a1 - m));
        l0 = a0 - lse;
        l1 = a1 - lse;
    }
    #pragma unroll
    for (int off = 32; off > 0; off >>= 1) {
        l0 += __shfl_down(l0, off, 64);
        l1 += __shfl_down(l1, off, 64);
    }
    __shared__ float s0[FTPB / 64], s1[FTPB / 64];
    int wid = threadIdx.x >> 6, lane = threadIdx.x & 63;
    if (lane == 0) { s0[wid] = l0; s1[wid] = l1; }
    __syncthreads();
    if (threadIdx.x == 0) {
        float t0 = 0.f, t1 = 0.f;
        #pragma unroll
        for (int k = 0; k < FTPB / 64; ++k) { t0 += s0[k]; t1 += s1[k]; }
        atomicAdd(&accum[0], t0);
        atomicAdd(&accum[1], t1);
    }
}

extern "C" void kernel_launch(void* const* d_in, const int* in_sizes, int n_in,
                              void* d_out, int out_size, void* d_ws, size_t ws_size,
                              hipStream_t stream) {
    const float* x  = (const float*)d_in[0];
    const int*   ei = (const int*)d_in[1];
    const float* W1 = (const float*)d_in[2];
    const float* b1 = (const float*)d_in[3];
    const float* W2 = (const float*)d_in[4];
    const float* b2 = (const float*)d_in[5];
    float* out = (float*)d_out;

    const int N = in_sizes[0];
    const int E = in_sizes[1] / 2;
    const int nbuck = (N + BNODES - 1) >> BSHIFT;
    const int gridN = (N + FTPB - 1) / FTPB;
    const int gridE = (E + FTPB - 1) / FTPB;

    size_t offPacked = 0;
    size_t offW      = offPacked + (size_t)nbuck * BSTRIDE * 4;
    size_t offU      = offW + (size_t)N * 8;
    size_t offGcur   = offU + (size_t)N * 4;
    size_t offDeg    = offGcur + (size_t)nbuck * 4;   // adjacent to gcur: one memset
    size_t offAccum  = offDeg + (size_t)N * 4;
    size_t need      = offAccum + (size_t)2 * nbuck * 4;

    if (ws_size >= need && nbuck <= MAXBUCK && N <= (1 << 17)) {
        unsigned* packed = (unsigned*)((char*)d_ws + offPacked);
        float2*   w      = (float2*)((char*)d_ws + offW);
        float*    u      = (float*)((char*)d_ws + offU);
        int*      gcur   = (int*)((char*)d_ws + offGcur);
        int*      deg    = (int*)((char*)d_ws + offDeg);
        float*    accum  = (float*)((char*)d_ws + offAccum);

        hipMemsetAsync(gcur, 0, (size_t)nbuck * 4 + (size_t)N * 4, stream);

        int epb = (((E + SORT_BLK - 1) / SORT_BLK) + 3) & ~3;

        k_sort<<<SORT_BLK, TPB, 0, stream>>>(ei, E, epb, nbuck, gcur, packed, deg);
        k_u<<<(N + TPB - 1) / TPB, TPB, 0, stream>>>(deg, x, u, N);
        k_csr_agg1<<<nbuck, TPB, 0, stream>>>(packed, deg, u, W1, b1, W2, w, N);
        k_agg2<<<nbuck, TPB, 0, stream>>>(packed, deg, (const float2*)w, b2, accum, N);
        k_reduce_final<<<1, RTPB, 0, stream>>>(accum, nbuck, out, 1.0f / (float)N);
    } else {
        int*   deg   = (int*)d_ws;
        float* t     = (float*)(deg + N);
        float* acc   = t + N;
        float* accum = acc + 2 * N;
        float* dinv  = accum + 2;
        float* u     = dinv + N;
        float2* w    = (float2*)(u + N);
        hipMemsetAsync(d_ws, 0, (size_t)(4 * N + 2) * sizeof(float), stream);
        k_hist<<<gridE, FTPB, 0, stream>>>(ei + E, E, deg);
        k_dinv_u<<<gridN, FTPB, 0, stream>>>(deg, x, dinv, u, N);
        k_scatter1<<<gridE, FTPB, 0, stream>>>(ei, E, u, t);
        k_node_mid_fb<<<gridN, FTPB, 0, stream>>>(dinv, u, t, W1, b1, W2, w, N);
        k_scatter2<<<gridE, FTPB, 0, stream>>>(ei, E, w, acc);
        k_node_out_fb<<<gridN, FTPB, 0, stream>>>(dinv, w, (const float2*)acc, b2, accum, N);
        k_finalize<<<1, 64, 0, stream>>>(accum, out, 1.0f / (float)N);
    }
}

// Round 6
// 160.916 us; speedup vs baseline: 1.7313x; 1.7313x over previous
//
#include <hip/hip_runtime.h>

// GCN 2-layer. R13 = verified R9 pipeline + 4-way-unrolled gather loops (MLP).
// R12 post-mortem: 3.2M scattered global atomicAdds in k_sort generated ~150MB
// of HBM-level RMW traffic (~45B per atomic; cross-XCD-coherent atomics don't
// coalesce in L2) -> k_sort 158us, total 278us. HW RULE: no global atomics on
// per-edge paths. Reverted to R9 (164.8us verified).
// R13 change: agg gather loops (u[src] / w[src], random L2-resident lines) are
// latency x outstanding-limited (~12K lines/CU x ~300cy / ~32 outstanding ~= 45us
// per pass, matches R6's 49.7us). Unroll segment loops 4-wide into independent
// accumulators -> 4 gathers in flight per thread.
//  k_sort  : bucket sort by dst>>7 (atomic reservation, fixed-stride regions)
//  k_csr   : per-bucket count/scan/place -> sorted srcs in-place + rptr + dinv/u
//  k_agg1  : atomic-free segmented sum of u[src] (4-way unrolled) + MLP -> w
//  k_agg2  : segmented float2 sum (4-way unrolled) + log_softmax + block partial
//  k_reduce_final : sum partials + 1/N
// packed word (pre-sort): bits[16:0]=src, bits[23:17]=dst&127; post-sort: src.

#define TPB 512
#define SORT_BLK 256
#define BSHIFT 7
#define BNODES 128
#define MAXBUCK 1024
#define BSTRIDE 6144      // words per bucket region; mean 4092, sigma ~64 -> 32 sigma

// ---------------- bucket sort (count+place fused, atomic reservation) --------

__global__ __launch_bounds__(TPB) void k_sort(const int* __restrict__ ei, int E, int epb,
                                              int nbuck, int* __restrict__ gcur,
                                              unsigned* __restrict__ packed) {
    __shared__ int h[MAXBUCK];
    for (int b = threadIdx.x; b < nbuck; b += TPB) h[b] = 0;
    __syncthreads();
    const int4* d4 = (const int4*)(ei + E);
    int nq = epb >> 2;
    int q0 = blockIdx.x * nq;
    for (int j = threadIdx.x; j < nq; j += TPB) {
        int q = q0 + j;
        int e = q << 2;
        if (e + 3 < E) {
            int4 v = d4[q];
            atomicAdd(&h[v.x >> BSHIFT], 1);
            atomicAdd(&h[v.y >> BSHIFT], 1);
            atomicAdd(&h[v.z >> BSHIFT], 1);
            atomicAdd(&h[v.w >> BSHIFT], 1);
        } else {
            for (int k = 0; k < 4; ++k)
                if (e + k < E) atomicAdd(&h[(ei + E)[e + k] >> BSHIFT], 1);
        }
    }
    __syncthreads();
    for (int b = threadIdx.x; b < nbuck; b += TPB) {
        int c = h[b];
        h[b] = c ? atomicAdd(&gcur[b], c) : 0;
    }
    __syncthreads();
    const int4* s4 = (const int4*)ei;
    for (int j = threadIdx.x; j < nq; j += TPB) {
        int q = q0 + j;
        int e = q << 2;
        if (e + 3 < E) {
            int4 vs = s4[q];
            int4 vd = d4[q];
            int b, p;
            b = vd.x >> BSHIFT; p = atomicAdd(&h[b], 1);
            packed[b * BSTRIDE + p] = ((unsigned)(vd.x & (BNODES - 1)) << 17) | (unsigned)vs.x;
            b = vd.y >> BSHIFT; p = atomicAdd(&h[b], 1);
            packed[b * BSTRIDE + p] = ((unsigned)(vd.y & (BNODES - 1)) << 17) | (unsigned)vs.y;
            b = vd.z >> BSHIFT; p = atomicAdd(&h[b], 1);
            packed[b * BSTRIDE + p] = ((unsigned)(vd.z & (BNODES - 1)) << 17) | (unsigned)vs.z;
            b = vd.w >> BSHIFT; p = atomicAdd(&h[b], 1);
            packed[b * BSTRIDE + p] = ((unsigned)(vd.w & (BNODES - 1)) << 17) | (unsigned)vs.w;
        } else {
            for (int k = 0; k < 4; ++k) {
                int ee = e + k;
                if (ee < E) {
                    int s = ei[ee], d = ei[E + ee];
                    int b = d >> BSHIFT;
                    int p = atomicAdd(&h[b], 1);
                    packed[b * BSTRIDE + p] = ((unsigned)(d & (BNODES - 1)) << 17) | (unsigned)s;
                }
            }
        }
    }
}

// ------- per-bucket deg -> dinv/u + in-place counting sort (CSR build) -------

__global__ __launch_bounds__(TPB) void k_csr(unsigned* __restrict__ packed,
                                             const int* __restrict__ gcur,
                                             const float* __restrict__ x,
                                             float* __restrict__ dinv,
                                             float* __restrict__ u,
                                             int* __restrict__ rptr, int N) {
    __shared__ int cnt[8][BNODES];
    __shared__ int eptr[BNODES];
    __shared__ unsigned stage[BSTRIDE];
    for (int k = threadIdx.x; k < 8 * BNODES; k += TPB) ((int*)cnt)[k] = 0;
    __syncthreads();
    int b = blockIdx.x;
    int sz = gcur[b];
    unsigned* base = packed + (size_t)b * BSTRIDE;
    const uint4* base4 = (const uint4*)base;
    int wv = threadIdx.x >> 6;
    int nq4 = sz >> 2;
    int half = nq4 >> 1;
    for (int j = threadIdx.x; j < half; j += TPB) {
        uint4 p = base4[j];
        uint4 q = base4[j + half];
        atomicAdd(&cnt[wv][(p.x >> 17) & 127], 1);
        atomicAdd(&cnt[wv][(p.y >> 17) & 127], 1);
        atomicAdd(&cnt[wv][(p.z >> 17) & 127], 1);
        atomicAdd(&cnt[wv][(p.w >> 17) & 127], 1);
        atomicAdd(&cnt[wv][(q.x >> 17) & 127], 1);
        atomicAdd(&cnt[wv][(q.y >> 17) & 127], 1);
        atomicAdd(&cnt[wv][(q.z >> 17) & 127], 1);
        atomicAdd(&cnt[wv][(q.w >> 17) & 127], 1);
    }
    for (int j = half * 8 + threadIdx.x; j < sz; j += TPB) {   // tail < 12 words
        unsigned p = base[j];
        atomicAdd(&cnt[wv][(p >> 17) & 127], 1);
    }
    __syncthreads();
    int tot = 0;
    if (threadIdx.x < BNODES) {
        #pragma unroll
        for (int c = 0; c < 8; ++c) tot += cnt[c][threadIdx.x];
        eptr[threadIdx.x] = tot;
    }
    __syncthreads();
    for (int d = 1; d < BNODES; d <<= 1) {
        int add = 0;
        if (threadIdx.x < BNODES && threadIdx.x >= d) add = eptr[threadIdx.x - d];
        __syncthreads();
        if (threadIdx.x < BNODES) eptr[threadIdx.x] += add;
        __syncthreads();
    }
    if (threadIdx.x < BNODES) {
        int t = threadIdx.x;
        int ex = eptr[t] - tot;
        int run = ex;
        #pragma unroll
        for (int c = 0; c < 8; ++c) { int v = cnt[c][t]; cnt[c][t] = run; run += v; }
        rptr[b * BNODES + t] = ex;
        int node = (b << BSHIFT) + t;
        if (node < N) {
            float di = rsqrtf((float)(tot + 1));   // +1 self-loop
            dinv[node] = di;
            u[node] = di * x[node];
        }
    }
    __syncthreads();
    for (int j = threadIdx.x; j < half; j += TPB) {
        uint4 p = base4[j];
        uint4 q = base4[j + half];
        int pos;
        pos = atomicAdd(&cnt[wv][(p.x >> 17) & 127], 1); stage[pos] = p.x & 0x1FFFF;
        pos = atomicAdd(&cnt[wv][(p.y >> 17) & 127], 1); stage[pos] = p.y & 0x1FFFF;
        pos = atomicAdd(&cnt[wv][(p.z >> 17) & 127], 1); stage[pos] = p.z & 0x1FFFF;
        pos = atomicAdd(&cnt[wv][(p.w >> 17) & 127], 1); stage[pos] = p.w & 0x1FFFF;
        pos = atomicAdd(&cnt[wv][(q.x >> 17) & 127], 1); stage[pos] = q.x & 0x1FFFF;
        pos = atomicAdd(&cnt[wv][(q.y >> 17) & 127], 1); stage[pos] = q.y & 0x1FFFF;
        pos = atomicAdd(&cnt[wv][(q.z >> 17) & 127], 1); stage[pos] = q.z & 0x1FFFF;
        pos = atomicAdd(&cnt[wv][(q.w >> 17) & 127], 1); stage[pos] = q.w & 0x1FFFF;
    }
    for (int j = half * 8 + threadIdx.x; j < sz; j += TPB) {
        unsigned p = base[j];
        int pos = atomicAdd(&cnt[wv][(p >> 17) & 127], 1);
        stage[pos] = p & 0x1FFFF;
    }
    __syncthreads();
    for (int k = threadIdx.x; k < sz; k += TPB) base[k] = stage[k];
}

// ------- layer-1: segmented sum (4-way unrolled gathers) + MLP -> w -------

__global__ __launch_bounds__(TPB) void k_agg1(const unsigned* __restrict__ sorted,
                                              const int* __restrict__ gcur,
                                              const int* __restrict__ rptr,
                                              const float* __restrict__ dinv,
                                              const float* __restrict__ u,
                                              const float* __restrict__ W1,
                                              const float* __restrict__ b1,
                                              const float* __restrict__ W2,
                                              float2* __restrict__ w, int N) {
    __shared__ float sW1[64], sb1[64], sW2[128];
    __shared__ int sptr[BNODES + 1];
    int b = blockIdx.x;
    if (threadIdx.x < 64) { sW1[threadIdx.x] = W1[threadIdx.x]; sb1[threadIdx.x] = b1[threadIdx.x]; }
    else if (threadIdx.x < 192) sW2[threadIdx.x - 64] = W2[threadIdx.x - 64];
    if (threadIdx.x < BNODES) sptr[threadIdx.x] = rptr[b * BNODES + threadIdx.x];
    if (threadIdx.x == 0) sptr[BNODES] = gcur[b];
    __syncthreads();
    int t = threadIdx.x >> 2, k = threadIdx.x & 3;
    const unsigned* base = sorted + (size_t)b * BSTRIDE;
    int s0 = sptr[t], s1 = sptr[t + 1];
    float s = 0.f;
    int j = s0 + k;
    // 4-way unroll: 4 independent gathers in flight per thread
    for (; j + 12 < s1; j += 16) {
        unsigned i0 = base[j], i1 = base[j + 4], i2 = base[j + 8], i3 = base[j + 12];
        float a0 = u[i0], a1 = u[i1], a2 = u[i2], a3 = u[i3];
        s += (a0 + a1) + (a2 + a3);
    }
    for (; j < s1; j += 4) s += u[base[j]];
    s += __shfl_xor(s, 1, 64);
    s += __shfl_xor(s, 2, 64);
    int node = (b << BSHIFT) + t;
    if (k == 0 && node < N) {
        float di = dinv[node];
        float sv = di * (s + u[node]);           // self-loop term dinv*u
        float z0 = 0.f, z1 = 0.f;
        #pragma unroll
        for (int jj = 0; jj < 64; ++jj) {
            float h = fmaxf(fmaf(sv, sW1[jj], sb1[jj]), 0.f);
            z0 = fmaf(h, sW2[2 * jj], z0);
            z1 = fmaf(h, sW2[2 * jj + 1], z1);
        }
        w[node] = make_float2(di * z0, di * z1); // pre-scaled by dinv[src]
    }
}

// ---- layer-2: segmented float2 sum (4-way unrolled) + log_softmax + partial ----

__global__ __launch_bounds__(TPB) void k_agg2(const unsigned* __restrict__ sorted,
                                              const int* __restrict__ gcur,
                                              const int* __restrict__ rptr,
                                              const float* __restrict__ dinv,
                                              const float2* __restrict__ w,
                                              const float* __restrict__ b2,
                                              float* __restrict__ accum, int N) {
    __shared__ int sptr[BNODES + 1];
    int b = blockIdx.x;
    if (threadIdx.x < BNODES) sptr[threadIdx.x] = rptr[b * BNODES + threadIdx.x];
    if (threadIdx.x == 0) sptr[BNODES] = gcur[b];
    __syncthreads();
    int t = threadIdx.x >> 2, k = threadIdx.x & 3;
    const unsigned* base = sorted + (size_t)b * BSTRIDE;
    int s0 = sptr[t], s1 = sptr[t + 1];
    float sx = 0.f, sy = 0.f;
    int j = s0 + k;
    for (; j + 12 < s1; j += 16) {
        unsigned i0 = base[j], i1 = base[j + 4], i2 = base[j + 8], i3 = base[j + 12];
        float2 v0 = w[i0], v1 = w[i1], v2 = w[i2], v3 = w[i3];
        sx += (v0.x + v1.x) + (v2.x + v3.x);
        sy += (v0.y + v1.y) + (v2.y + v3.y);
    }
    for (; j < s1; j += 4) {
        float2 v = w[base[j]];
        sx += v.x;
        sy += v.y;
    }
    sx += __shfl_xor(sx, 1, 64); sx += __shfl_xor(sx, 2, 64);
    sy += __shfl_xor(sy, 1, 64); sy += __shfl_xor(sy, 2, 64);
    int node = (b << BSHIFT) + t;
    float l0 = 0.f, l1 = 0.f;
    if (k == 0 && node < N) {
        float di = dinv[node];
        float2 wi = w[node];
        float a0 = di * (sx + wi.x) + b2[0];
        float a1 = di * (sy + wi.y) + b2[1];
        float m = fmaxf(a0, a1);
        float lse = m + logf(expf(a0 - m) + expf(a1 - m));
        l0 = a0 - lse;
        l1 = a1 - lse;
    }
    #pragma unroll
    for (int off = 32; off > 0; off >>= 1) {
        l0 += __shfl_down(l0, off, 64);
        l1 += __shfl_down(l1, off, 64);
    }
    __shared__ float r0[TPB / 64], r1[TPB / 64];
    int wid = threadIdx.x >> 6, lane = threadIdx.x & 63;
    if (lane == 0) { r0[wid] = l0; r1[wid] = l1; }
    __syncthreads();
    if (threadIdx.x == 0) {
        float t0 = 0.f, t1 = 0.f;
        #pragma unroll
        for (int kk = 0; kk < TPB / 64; ++kk) { t0 += r0[kk]; t1 += r1[kk]; }
        accum[2 * b]     = t0;   // private slot, plain store
        accum[2 * b + 1] = t1;
    }
}

// ---------------- final reduction over per-block partials ----------------

#define RTPB 1024
__global__ __launch_bounds__(RTPB) void k_reduce_final(const float* __restrict__ accum,
                                                       int nb, float* __restrict__ out,
                                                       float invN) {
    float t0 = 0.f, t1 = 0.f;
    for (int i = threadIdx.x; i < nb; i += RTPB) {
        t0 += accum[2 * i];
        t1 += accum[2 * i + 1];
    }
    #pragma unroll
    for (int off = 32; off > 0; off >>= 1) {
        t0 += __shfl_down(t0, off, 64);
        t1 += __shfl_down(t1, off, 64);
    }
    __shared__ float s0[RTPB / 64], s1[RTPB / 64];
    int wid = threadIdx.x >> 6, lane = threadIdx.x & 63;
    if (lane == 0) { s0[wid] = t0; s1[wid] = t1; }
    __syncthreads();
    if (threadIdx.x == 0) {
        float a = 0.f, b = 0.f;
        #pragma unroll
        for (int k = 0; k < RTPB / 64; ++k) { a += s0[k]; b += s1[k]; }
        out[0] = a * invN;
        out[1] = b * invN;
    }
}

__global__ void k_finalize(const float* __restrict__ accum, float* __restrict__ out, float invN) {
    out[0] = accum[0] * invN;
    out[1] = accum[1] * invN;
}

// ---------------- fallback (global-atomic path) ----------------

#define FTPB 256
__global__ void k_hist(const int* __restrict__ dst, int E, int* __restrict__ deg) {
    int e = blockIdx.x * FTPB + threadIdx.x;
    if (e < E) atomicAdd(&deg[dst[e]], 1);
}
__global__ void k_dinv_u(const int* __restrict__ deg, const float* __restrict__ x,
                         float* __restrict__ dinv, float* __restrict__ u, int N) {
    int i = blockIdx.x * FTPB + threadIdx.x;
    if (i < N) {
        float di = rsqrtf((float)(deg[i] + 1));
        dinv[i] = di;
        u[i] = di * x[i];
    }
}
__global__ void k_scatter1(const int* __restrict__ ei, int E,
                           const float* __restrict__ u, float* __restrict__ t) {
    int e = blockIdx.x * FTPB + threadIdx.x;
    if (e < E) atomicAdd(&t[ei[E + e]], u[ei[e]]);
}
__global__ void k_node_mid_fb(const float* __restrict__ dinv, const float* __restrict__ u,
                              const float* __restrict__ t,
                              const float* __restrict__ W1, const float* __restrict__ b1,
                              const float* __restrict__ W2, float2* __restrict__ w, int N) {
    __shared__ float sW1[64], sb1[64], sW2[128];
    if (threadIdx.x < 64) { sW1[threadIdx.x] = W1[threadIdx.x]; sb1[threadIdx.x] = b1[threadIdx.x]; }
    if (threadIdx.x < 128) sW2[threadIdx.x] = W2[threadIdx.x];
    __syncthreads();
    int i = blockIdx.x * FTPB + threadIdx.x;
    if (i < N) {
        float di = dinv[i];
        float s = di * (t[i] + u[i]);
        float z0 = 0.f, z1 = 0.f;
        #pragma unroll
        for (int j = 0; j < 64; ++j) {
            float h = fmaxf(fmaf(s, sW1[j], sb1[j]), 0.f);
            z0 = fmaf(h, sW2[2 * j], z0);
            z1 = fmaf(h, sW2[2 * j + 1], z1);
        }
        w[i] = make_float2(di * z0, di * z1);
    }
}
__global__ void k_scatter2(const int* __restrict__ ei, int E,
                           const float2* __restrict__ w, float* __restrict__ acc) {
    int e = blockIdx.x * FTPB + threadIdx.x;
    if (e < E) {
        float2 ws = w[ei[e]];
        int d = ei[E + e];
        atomicAdd(&acc[2 * d], ws.x);
        atomicAdd(&acc[2 * d + 1], ws.y);
    }
}
__global__ void k_node_out_fb(const float* __restrict__ dinv, const float2* __restrict__ w,
                              const float2* __restrict__ acc, const float* __restrict__ b2,
                              float* __restrict__ accum, int N) {
    int i = blockIdx.x * FTPB + threadIdx.x;
    float l0 = 0.f, l1 = 0.f;
    if (i < N) {
        float di = dinv[i];
        float2 a = acc[i];
        float2 ww = w[i];
        float a0 = di * (a.x + ww.x) + b2[0];
        float a1 = di * (a.y + ww.y) + b2[1];
        float m = fmaxf(a0, a1);
        float lse = m + logf(expf(a0 - m) + expf(a1 - m));
        l0 = a0 - lse;
        l1 = a1 - lse;
    }
    #pragma unroll
    for (int off = 32; off > 0; off >>= 1) {
        l0 += __shfl_down(l0, off, 64);
        l1 += __shfl_down(l1, off, 64);
    }
    __shared__ float s0[FTPB / 64], s1[FTPB / 64];
    int wid = threadIdx.x >> 6, lane = threadIdx.x & 63;
    if (lane == 0) { s0[wid] = l0; s1[wid] = l1; }
    __syncthreads();
    if (threadIdx.x == 0) {
        float t0 = 0.f, t1 = 0.f;
        #pragma unroll
        for (int k = 0; k < FTPB / 64; ++k) { t0 += s0[k]; t1 += s1[k]; }
        atomicAdd(&accum[0], t0);
        atomicAdd(&accum[1], t1);
    }
}

extern "C" void kernel_launch(void* const* d_in, const int* in_sizes, int n_in,
                              void* d_out, int out_size, void* d_ws, size_t ws_size,
                              hipStream_t stream) {
    const float* x  = (const float*)d_in[0];
    const int*   ei = (const int*)d_in[1];
    const float* W1 = (const float*)d_in[2];
    const float* b1 = (const float*)d_in[3];
    const float* W2 = (const float*)d_in[4];
    const float* b2 = (const float*)d_in[5];
    float* out = (float*)d_out;

    const int N = in_sizes[0];
    const int E = in_sizes[1] / 2;
    const int nbuck = (N + BNODES - 1) >> BSHIFT;
    const int gridN = (N + FTPB - 1) / FTPB;
    const int gridE = (E + FTPB - 1) / FTPB;

    size_t offPacked = 0;
    size_t offW      = offPacked + (size_t)nbuck * BSTRIDE * 4;
    size_t offDinv   = offW + (size_t)N * 8;
    size_t offU      = offDinv + (size_t)N * 4;
    size_t offGcur   = offU + (size_t)N * 4;
    size_t offAccum  = offGcur + (size_t)nbuck * 4;
    size_t offRptr   = offAccum + (size_t)2 * nbuck * 4;
    size_t need      = offRptr + (size_t)nbuck * BNODES * 4;

    if (ws_size >= need && nbuck <= MAXBUCK && N <= (1 << 17)) {
        unsigned* packed = (unsigned*)((char*)d_ws + offPacked);
        float2*   w      = (float2*)((char*)d_ws + offW);
        float*    dinv   = (float*)((char*)d_ws + offDinv);
        float*    u      = (float*)((char*)d_ws + offU);
        int*      gcur   = (int*)((char*)d_ws + offGcur);
        float*    accum  = (float*)((char*)d_ws + offAccum);
        int*      rptr   = (int*)((char*)d_ws + offRptr);

        hipMemsetAsync(gcur, 0, (size_t)nbuck * 4, stream);

        int epb = (((E + SORT_BLK - 1) / SORT_BLK) + 3) & ~3;

        k_sort<<<SORT_BLK, TPB, 0, stream>>>(ei, E, epb, nbuck, gcur, packed);
        k_csr<<<nbuck, TPB, 0, stream>>>(packed, gcur, x, dinv, u, rptr, N);
        k_agg1<<<nbuck, TPB, 0, stream>>>(packed, gcur, rptr, dinv, u, W1, b1, W2, w, N);
        k_agg2<<<nbuck, TPB, 0, stream>>>(packed, gcur, rptr, dinv, (const float2*)w, b2, accum, N);
        k_reduce_final<<<1, RTPB, 0, stream>>>(accum, nbuck, out, 1.0f / (float)N);
    } else {
        int*   deg   = (int*)d_ws;
        float* t     = (float*)(deg + N);
        float* acc   = t + N;
        float* accum = acc + 2 * N;
        float* dinv  = accum + 2;
        float* u     = dinv + N;
        float2* w    = (float2*)(u + N);
        hipMemsetAsync(d_ws, 0, (size_t)(4 * N + 2) * sizeof(float), stream);
        k_hist<<<gridE, FTPB, 0, stream>>>(ei + E, E, deg);
        k_dinv_u<<<gridN, FTPB, 0, stream>>>(deg, x, dinv, u, N);
        k_scatter1<<<gridE, FTPB, 0, stream>>>(ei, E, u, t);
        k_node_mid_fb<<<gridN, FTPB, 0, stream>>>(dinv, u, t, W1, b1, W2, w, N);
        k_scatter2<<<gridE, FTPB, 0, stream>>>(ei, E, w, acc);
        k_node_out_fb<<<gridN, FTPB, 0, stream>>>(dinv, w, (const float2*)acc, b2, accum, N);
        k_finalize<<<1, 64, 0, stream>>>(accum, out, 1.0f / (float)N);
    }
}